// Round 3
// 517.812 us; speedup vs baseline: 1.2677x; 1.2677x over previous
//
#include <hip/hip_runtime.h>

#define D_MODEL 1024
#define LSEQ    8192
#define NC      8192            // complex FFT size = (2*L)/2
#define PI_F    3.14159265358979323846f
#define TWO_PI_OVER_N 3.8349519697141029e-4f   // 2*pi/16384
#define R2F  0.70710678118654752440f           // cos(pi/4)
#define C18F 0.92387953251128675613f           // cos(pi/8)
#define S18F 0.38268343236508977173f           // sin(pi/8)

// Extended XOR swizzle on LDS float2 index:
//  (p>>7)&15 : spreads the bit-reversed scatter of the spectral multiply pass
//  (p>>3)&7  : spreads the small-stride patterns of the fused radix-8/16 passes
// Bijective (bits>=4 recoverable -> invert bit3 via bit10, then bits0-2).
__device__ __forceinline__ int sw(int p) { return p ^ ((p >> 7) & 15) ^ ((p >> 3) & 7); }
__device__ __forceinline__ int rev13(int x) { return (int)(__brev((unsigned)x) >> 19); }
__device__ __forceinline__ float2 cmulf(float2 a, float2 b) {
    return make_float2(a.x*b.x - a.y*b.y, a.x*b.y + a.y*b.x);
}

// ---- radix-2 butterflies -------------------------------------------------
// DIF: a' = a+b ; b' = (a-b)*w, w=(c,s)
__device__ __forceinline__ void bf_dif(float2& a, float2& b, float c, float s) {
    float tx = a.x - b.x, ty = a.y - b.y;
    a.x += b.x; a.y += b.y;
    b.x = tx*c - ty*s; b.y = tx*s + ty*c;
}
__device__ __forceinline__ void bf_dif1(float2& a, float2& b) {        // w = 1
    float tx = a.x - b.x, ty = a.y - b.y;
    a.x += b.x; a.y += b.y;
    b.x = tx; b.y = ty;
}
__device__ __forceinline__ void bf_dif_mi(float2& a, float2& b) {      // w = -i
    float tx = a.x - b.x, ty = a.y - b.y;
    a.x += b.x; a.y += b.y;
    b.x = ty; b.y = -tx;
}
// DIT: b'' = b*w ; a' = a+b'' ; b' = a-b''
__device__ __forceinline__ void bf_dit(float2& a, float2& b, float c, float s) {
    float bx = b.x*c - b.y*s, by = b.x*s + b.y*c;
    b.x = a.x - bx; b.y = a.y - by;
    a.x += bx; a.y += by;
}
__device__ __forceinline__ void bf_dit1(float2& a, float2& b) {        // w = 1
    float bx = b.x, by = b.y;
    b.x = a.x - bx; b.y = a.y - by;
    a.x += bx; a.y += by;
}
__device__ __forceinline__ void bf_dit_pi(float2& a, float2& b) {      // w = +i
    float bx = -b.y, by = b.x;
    b.x = a.x - bx; b.y = a.y - by;
    a.x += bx; a.y += by;
}
// DIT a-output only: a' = a + w*b   (for the final level where b' is dead)
__device__ __forceinline__ void bf_dit_a(float2& a, float2 b, float c, float s) {
    a.x += b.x*c - b.y*s; a.y += b.x*s + b.y*c;
}

// ---- fused forward pass: DIF levels H, H/2, H/4 (H in {512, 64}) ---------
// Identical butterfly graph to three radix-2 passes -> layout preserved.
template<int H>
__device__ __forceinline__ void fwd_pass8(float2* s, int tid) {
    const float astep = -PI_F / (float)H;
    for (int gg = 0; gg < 4; ++gg) {
        int gi   = tid + gg * 256;              // 1024 groups of 8
        int q    = gi & (H/4 - 1);
        int base = (gi - q) * 8 + q;            // block*2H + q
        float2 v[8];
        #pragma unroll
        for (int m = 0; m < 8; ++m) v[m] = s[sw(base + m*(H/4))];
        float a = astep * (float)q;
        float c1,s1,c2,s2,c4,s4;
        __sincosf(a,     &s1, &c1);
        __sincosf(a+a,   &s2, &c2);
        __sincosf(4.f*a, &s4, &c4);
        // level H: pairs (m, m+4), w = e^{ia} * e^{-i pi m/4}
        bf_dif(v[0], v[4], c1, s1);
        bf_dif(v[1], v[5], R2F*(c1+s1), R2F*(s1-c1));
        bf_dif(v[2], v[6], s1, -c1);
        bf_dif(v[3], v[7], R2F*(s1-c1), -R2F*(c1+s1));
        // level H/2: pairs (m, m+2); odd pairs get extra *(-i)
        bf_dif(v[0], v[2], c2, s2);  bf_dif(v[4], v[6], c2, s2);
        bf_dif(v[1], v[3], s2, -c2); bf_dif(v[5], v[7], s2, -c2);
        // level H/4: all pairs (m, m+1), w = e^{i4a}
        bf_dif(v[0], v[1], c4, s4); bf_dif(v[2], v[3], c4, s4);
        bf_dif(v[4], v[5], c4, s4); bf_dif(v[6], v[7], c4, s4);
        #pragma unroll
        for (int m = 0; m < 8; ++m) s[sw(base + m*(H/4))] = v[m];
    }
}

// ---- DIF levels 8,4,2,1 on a contiguous 16-block (all twiddles const) ----
__device__ __forceinline__ void dif16(float2* v) {
    // level 8: (i, i+8), w = e^{-i pi i/8}
    bf_dif1 (v[0], v[8]);
    bf_dif  (v[1], v[9],   C18F, -S18F);
    bf_dif  (v[2], v[10],  R2F,  -R2F);
    bf_dif  (v[3], v[11],  S18F, -C18F);
    bf_dif_mi(v[4], v[12]);
    bf_dif  (v[5], v[13], -S18F, -C18F);
    bf_dif  (v[6], v[14], -R2F,  -R2F);
    bf_dif  (v[7], v[15], -C18F, -S18F);
    // level 4: (i, i+4) in 8-blocks, w = e^{-i pi i/4}
    bf_dif1 (v[0], v[4]);              bf_dif1 (v[8],  v[12]);
    bf_dif  (v[1], v[5],  R2F, -R2F);  bf_dif  (v[9],  v[13],  R2F, -R2F);
    bf_dif_mi(v[2], v[6]);             bf_dif_mi(v[10], v[14]);
    bf_dif  (v[3], v[7], -R2F, -R2F);  bf_dif  (v[11], v[15], -R2F, -R2F);
    // level 2: (i, i+2) in 4-blocks, w = 1 or -i
    bf_dif1 (v[0], v[2]); bf_dif1 (v[4], v[6]); bf_dif1 (v[8], v[10]); bf_dif1 (v[12], v[14]);
    bf_dif_mi(v[1], v[3]); bf_dif_mi(v[5], v[7]); bf_dif_mi(v[9], v[11]); bf_dif_mi(v[13], v[15]);
    // level 1
    bf_dif1(v[0], v[1]); bf_dif1(v[2], v[3]);  bf_dif1(v[4], v[5]);  bf_dif1(v[6], v[7]);
    bf_dif1(v[8], v[9]); bf_dif1(v[10],v[11]); bf_dif1(v[12],v[13]); bf_dif1(v[14],v[15]);
}

// ---- full forward FFT: global (zero-padded) -> LDS, bit-reversed output --
// Pass1 fuses the zero-padded upper half: reads 4 float2/group from global,
// synthesizes all 8 (levels 4096,2048,1024). Then H=512, H=64, then dif16.
// SAVE: capture the 16 loaded x-values per thread (reused by the epilogue).
template<bool SAVE>
__device__ __forceinline__ void fwd_fft(float2* s, int tid,
                                        const float2* __restrict__ g, float2* xr) {
    {
        const float astep = -PI_F / 4096.0f;
        for (int gg = 0; gg < 4; ++gg) {
            int q = tid + gg * 256;             // 0..1023
            float2 v[8];
            #pragma unroll
            for (int m = 0; m < 4; ++m) {
                v[m] = g[q + m*1024];
                if (SAVE) xr[gg*4 + m] = v[m];
            }
            float a = astep * (float)q;
            float c1,s1,c2,s2,c4,s4;
            __sincosf(a,     &s1, &c1);
            __sincosf(a+a,   &s2, &c2);
            __sincosf(4.f*a, &s4, &c4);
            // level 4096 vs zero upper half: v[m+4] = v[m] * (e^{ia} e^{-i pi m/4})
            float wc, ws;
            wc = c1;            ws = s1;             v[4] = make_float2(v[0].x*wc - v[0].y*ws, v[0].x*ws + v[0].y*wc);
            wc = R2F*(c1+s1);   ws = R2F*(s1-c1);    v[5] = make_float2(v[1].x*wc - v[1].y*ws, v[1].x*ws + v[1].y*wc);
            wc = s1;            ws = -c1;            v[6] = make_float2(v[2].x*wc - v[2].y*ws, v[2].x*ws + v[2].y*wc);
            wc = R2F*(s1-c1);   ws = -R2F*(c1+s1);   v[7] = make_float2(v[3].x*wc - v[3].y*ws, v[3].x*ws + v[3].y*wc);
            // level 2048
            bf_dif(v[0], v[2], c2, s2);  bf_dif(v[4], v[6], c2, s2);
            bf_dif(v[1], v[3], s2, -c2); bf_dif(v[5], v[7], s2, -c2);
            // level 1024
            bf_dif(v[0], v[1], c4, s4); bf_dif(v[2], v[3], c4, s4);
            bf_dif(v[4], v[5], c4, s4); bf_dif(v[6], v[7], c4, s4);
            #pragma unroll
            for (int m = 0; m < 8; ++m) s[sw(q + m*1024)] = v[m];
        }
    }
    __syncthreads();
    fwd_pass8<512>(s, tid);
    __syncthreads();
    fwd_pass8<64>(s, tid);
    __syncthreads();
    for (int gg = 0; gg < 2; ++gg) {            // levels 8,4,2,1
        int base = (tid + gg * 256) << 4;
        float2 v[16];
        #pragma unroll
        for (int m = 0; m < 16; ++m) v[m] = s[sw(base + m)];
        dif16(v);
        #pragma unroll
        for (int m = 0; m < 16; ++m) s[sw(base + m)] = v[m];
    }
}

// ---- DIT levels 1,2,4,8 on a contiguous 16-block (const twiddles, +i) ----
__device__ __forceinline__ void dit16(float2* v) {
    // level 1
    bf_dit1(v[0], v[1]); bf_dit1(v[2], v[3]);  bf_dit1(v[4], v[5]);  bf_dit1(v[6], v[7]);
    bf_dit1(v[8], v[9]); bf_dit1(v[10],v[11]); bf_dit1(v[12],v[13]); bf_dit1(v[14],v[15]);
    // level 2: w = 1 or +i
    bf_dit1 (v[0], v[2]); bf_dit_pi(v[1], v[3]);
    bf_dit1 (v[4], v[6]); bf_dit_pi(v[5], v[7]);
    bf_dit1 (v[8], v[10]); bf_dit_pi(v[9], v[11]);
    bf_dit1 (v[12],v[14]); bf_dit_pi(v[13],v[15]);
    // level 4: w = e^{+i pi (i&3)/4}
    bf_dit1 (v[0], v[4]);             bf_dit1 (v[8],  v[12]);
    bf_dit  (v[1], v[5],  R2F, R2F);  bf_dit  (v[9],  v[13],  R2F, R2F);
    bf_dit_pi(v[2], v[6]);            bf_dit_pi(v[10], v[14]);
    bf_dit  (v[3], v[7], -R2F, R2F);  bf_dit  (v[11], v[15], -R2F, R2F);
    // level 8: w = e^{+i pi i/8}
    bf_dit1 (v[0], v[8]);
    bf_dit  (v[1], v[9],   C18F, S18F);
    bf_dit  (v[2], v[10],  R2F,  R2F);
    bf_dit  (v[3], v[11],  S18F, C18F);
    bf_dit_pi(v[4], v[12]);
    bf_dit  (v[5], v[13], -S18F, C18F);
    bf_dit  (v[6], v[14], -R2F,  R2F);
    bf_dit  (v[7], v[15], -C18F, S18F);
}

// ---- fused inverse pass: DIT levels H, 2H, 4H (H in {16, 128}) -----------
template<int H>
__device__ __forceinline__ void inv_pass8(float2* s, int tid) {
    const float bstep = PI_F / (float)(4*H);
    for (int gg = 0; gg < 4; ++gg) {
        int gi   = tid + gg * 256;
        int q    = gi & (H - 1);
        int base = (gi - q) * 8 + q;            // block*8H + q
        float2 v[8];
        #pragma unroll
        for (int m = 0; m < 8; ++m) v[m] = s[sw(base + m*H)];
        float bb = bstep * (float)q;
        float cb,sb,c2,s2,c4,s4;
        __sincosf(bb,      &sb, &cb);
        __sincosf(bb+bb,   &s2, &c2);
        __sincosf(4.f*bb,  &s4, &c4);
        // level H: all pairs (m, m+1), w = e^{i4b}
        bf_dit(v[0],v[1],c4,s4); bf_dit(v[2],v[3],c4,s4);
        bf_dit(v[4],v[5],c4,s4); bf_dit(v[6],v[7],c4,s4);
        // level 2H: (m, m+2); odd pairs get extra *(+i)
        bf_dit(v[0],v[2], c2,s2);  bf_dit(v[4],v[6], c2,s2);
        bf_dit(v[1],v[3],-s2,c2);  bf_dit(v[5],v[7],-s2,c2);
        // level 4H: (m, m+4), w = e^{ib} e^{+i pi m/4}
        bf_dit(v[0],v[4],  cb, sb);
        bf_dit(v[1],v[5],  R2F*(cb-sb), R2F*(sb+cb));
        bf_dit(v[2],v[6], -sb, cb);
        bf_dit(v[3],v[7], -R2F*(sb+cb), R2F*(cb-sb));
        #pragma unroll
        for (int m = 0; m < 8; ++m) s[sw(base + m*H)] = v[m];
    }
}

// ---- last inverse pass (levels 1024,2048,4096) fused with epilogue -------
// Output keeps only time samples 0..8191 = complex n in [0,4096): that is
// exactly m = 0..3 of each group (q + m*1024). Level 4096 only needs the
// a-side outputs for those, and the store loop MUST stop at m<4 (writing
// m>=4 runs past the 4096-float2 channel -> OOB on the last channel).
__device__ __forceinline__ void inv_last_out(const float2* s, int tid,
                                             const float2* xr,
                                             float2* __restrict__ ov, float Dd) {
    const float bstep = PI_F / 4096.0f;
    for (int gg = 0; gg < 4; ++gg) {
        int q = tid + gg * 256;                 // single 8192-block
        float2 v[8];
        #pragma unroll
        for (int m = 0; m < 8; ++m) v[m] = s[sw(q + m*1024)];
        float bb = bstep * (float)q;
        float cb,sb,c2,s2,c4,s4;
        __sincosf(bb,      &sb, &cb);
        __sincosf(bb+bb,   &s2, &c2);
        __sincosf(4.f*bb,  &s4, &c4);
        // level 1024
        bf_dit(v[0],v[1],c4,s4); bf_dit(v[2],v[3],c4,s4);
        bf_dit(v[4],v[5],c4,s4); bf_dit(v[6],v[7],c4,s4);
        // level 2048
        bf_dit(v[0],v[2], c2,s2);  bf_dit(v[4],v[6], c2,s2);
        bf_dit(v[1],v[3],-s2,c2);  bf_dit(v[5],v[7],-s2,c2);
        // level 4096: only a-outputs (m=0..3) are kept
        bf_dit_a(v[0], v[4],  cb, sb);
        bf_dit_a(v[1], v[5],  R2F*(cb-sb), R2F*(sb+cb));
        bf_dit_a(v[2], v[6], -sb, cb);
        bf_dit_a(v[3], v[7], -R2F*(sb+cb), R2F*(cb-sb));
        #pragma unroll
        for (int m = 0; m < 4; ++m) {
            int n = q + m*1024;
            float2 xx = xr[gg*4 + m];
            ov[n] = make_float2(v[m].x + xx.x * Dd, v[m].y + xx.y * Dd);
        }
    }
}

// ---------------------------------------------------------------------------
// Kernel 1: implicit-filter MLP + output projection + exponential modulation.
// All weight reads are wave-uniform: readfirstlane forces SGPR addressing so
// they become s_load broadcasts instead of 6.7k per-lane VMEM loads/thread.
// ---------------------------------------------------------------------------
__global__ void __launch_bounds__(256) hyena_filter_k(
    const float* __restrict__ W1, const float* __restrict__ b1,
    const float* __restrict__ freq,
    const float* __restrict__ W2, const float* __restrict__ b2,
    const float* __restrict__ W3, const float* __restrict__ b3,
    const float* __restrict__ Wout,
    float* __restrict__ kout)
{
    __shared__ float zbuf[64][35];   // pad 33->35: (3p+e)%32 -> conflict-free
    __shared__ float abuf[64][65];   // pad 64->65
    __shared__ float bbuf[64][65];

    const int tid = threadIdx.x;
    const int pbase = blockIdx.x * 64;

    // phase 0: positional embedding z[p][0..32]
    for (int idx = tid; idx < 64 * 33; idx += 256) {
        int p = idx & 63, e = idx >> 6;
        int gp = pbase + p;
        float w = 7.6699039394282907e-4f * (float)gp;   // 2*pi*gp/8192
        float val;
        if (e == 0) {
            val = (float)gp / 8191.0f;
        } else if (e < 17) {
            float f = 1.0e-4f + (float)(e - 1) * ((15.0f - 1.0e-4f) / 15.0f);
            val = cosf(f * w);
        } else {
            float f = 1.0e-4f + (float)(e - 17) * ((15.0f - 1.0e-4f) / 15.0f);
            val = -sinf(f * w);
        }
        zbuf[p][e] = val;
    }
    __syncthreads();

    const int p  = tid & 63;                                   // lane-varying
    const int ob = __builtin_amdgcn_readfirstlane(tid >> 6) * 16;  // wave-uniform SGPR

    // layer 1: 33 -> 64, sin(freq * (z@W1 + b1))
    {
        float acc[16];
        #pragma unroll
        for (int oo = 0; oo < 16; ++oo) acc[oo] = b1[ob + oo];
        #pragma unroll
        for (int e = 0; e < 33; ++e) {
            float ae = zbuf[p][e];
            const float* wr = W1 + e * 64 + ob;
            #pragma unroll
            for (int oo = 0; oo < 16; ++oo) acc[oo] += ae * wr[oo];
        }
        #pragma unroll
        for (int oo = 0; oo < 16; ++oo) abuf[p][ob + oo] = __sinf(freq[ob + oo] * acc[oo]);
    }
    __syncthreads();
    // layer 2
    {
        float acc[16];
        #pragma unroll
        for (int oo = 0; oo < 16; ++oo) acc[oo] = b2[ob + oo];
        #pragma unroll
        for (int e = 0; e < 64; ++e) {
            float ae = abuf[p][e];
            const float* wr = W2 + e * 64 + ob;
            #pragma unroll
            for (int oo = 0; oo < 16; ++oo) acc[oo] += ae * wr[oo];
        }
        #pragma unroll
        for (int oo = 0; oo < 16; ++oo) bbuf[p][ob + oo] = __sinf(freq[ob + oo] * acc[oo]);
    }
    __syncthreads();
    // layer 3
    {
        float acc[16];
        #pragma unroll
        for (int oo = 0; oo < 16; ++oo) acc[oo] = b3[ob + oo];
        #pragma unroll
        for (int e = 0; e < 64; ++e) {
            float ae = bbuf[p][e];
            const float* wr = W3 + e * 64 + ob;
            #pragma unroll
            for (int oo = 0; oo < 16; ++oo) acc[oo] += ae * wr[oo];
        }
        #pragma unroll
        for (int oo = 0; oo < 16; ++oo) abuf[p][ob + oo] = __sinf(freq[ob + oo] * acc[oo]);
    }
    __syncthreads();

    // out projection (no bias, no sin) + decay, write k[d][l].
    // Wave handles a CONTIGUOUS 64-channel chunk -> Wout rows are consecutive
    // scalar dwordx8 loads.
    {
        float areg[64];
        #pragma unroll
        for (int e = 0; e < 64; ++e) areg[e] = abuf[p][e];
        const int gp = pbase + p;
        const float t = (float)gp / 8191.0f;
        const float mind  = -3.0701134573253940f;    // log(0.01)/1.5
        const float dstep = -0.012004353694331942f;  // (log(.01)/.3 - log(.01)/1.5)/1023
        const int dd0 = blockIdx.y * 256 + (ob << 2);
        for (int ic = 0; ic < 8; ++ic) {
            float acc[8];
            #pragma unroll
            for (int ii = 0; ii < 8; ++ii) acc[ii] = 0.0f;
            #pragma unroll
            for (int o = 0; o < 64; ++o) {
                const float* wr = Wout + o * 1024 + dd0 + ic * 8;
                float ao = areg[o];
                #pragma unroll
                for (int ii = 0; ii < 8; ++ii) acc[ii] += ao * wr[ii];
            }
            #pragma unroll
            for (int ii = 0; ii < 8; ++ii) {
                int dd = dd0 + ic * 8 + ii;
                float delta = fabsf(mind + dstep * (float)dd);
                kout[(size_t)dd * LSEQ + gp] = acc[ii] * __expf(-t * delta);
            }
        }
    }
}

// ---------------------------------------------------------------------------
// Kernel 2: per-channel FFT causal convolution + skip.
// Radix-8/16 fused passes: 4 LDS round-trips per FFT instead of 13, first
// fwd pass reads global directly (zero-pad folded), last inv pass writes
// global directly (skip fused, m<4 only). Butterfly graph identical to the
// radix-2 chain of the verified baseline.
// ---------------------------------------------------------------------------
__global__ void __launch_bounds__(256) hyena_conv_k(
    const float* __restrict__ x, const float* kin,
    const float* __restrict__ Dvec, float* out)
{
    __shared__ float2 s[NC];                     // 64 KB
    const int tid = threadIdx.x;
    const int d = blockIdx.x;
    const float Dd = Dvec[d];
    const float invN = 1.0f / 16384.0f;

    // ---- phase A: FFT of filter k[d], unpack spectrum into registers ----
    fwd_fft<false>(s, tid, (const float2*)(kin + (size_t)d * LSEQ), nullptr);
    __syncthreads();

    float2 Kk[16], Km[16];   // K[k]/N and K[8192-k]/N for k = tid + j*256
    #pragma unroll
    for (int j = 0; j < 16; ++j) {
        int k = tid + j * 256;
        if (k == 0) {
            float2 C0 = s[0];                       // sw(0)==0
            Kk[0] = make_float2((C0.x + C0.y) * invN, (C0.x - C0.y) * invN); // (K[0],K[8192])/N
            float2 C = s[1];                        // C[4096] at rev13(4096)=1, sw(1)==1
            Km[0] = make_float2(C.x * invN, -C.y * invN);                    // conj(C)/N
        } else {
            int m = NC - k;
            float2 Ck = s[sw(rev13(k))], Cm = s[sw(rev13(m))];
            float sn, cs;
            __sincosf(TWO_PI_OVER_N * (float)k, &sn, &cs);   // w = (cs,-sn)
            float2 E = make_float2(Ck.x + Cm.x, Ck.y - Cm.y); // Ck + conj(Cm)
            float2 O = make_float2(Ck.x - Cm.x, Ck.y + Cm.y); // Ck - conj(Cm)
            float2 WO = make_float2(O.x * cs + O.y * sn, -O.x * sn + O.y * cs); // w*O
            float2 T = make_float2(-WO.y, WO.x);              // i*w*O
            Kk[j] = make_float2(0.5f * invN * (E.x - T.x),  0.5f * invN * (E.y - T.y));
            Km[j] = make_float2(0.5f * invN * (E.x + T.x), -0.5f * invN * (E.y + T.y)); // conj(E+T)/2N
        }
    }

    // ---- per-batch: FFT(x) -> multiply -> IFFT (+ x*D fused) ----
    for (int b = 0; b < 2; ++b) {
        __syncthreads();   // prior readers of s are done
        const size_t base = ((size_t)b * D_MODEL + d) * LSEQ;
        float2 xr[16];
        fwd_fft<true>(s, tid, (const float2*)(x + base), xr);
        __syncthreads();

        // unpack U, multiply by filter spectrum, repack Z2 (x2 folded in),
        // all in bit-reversed layout.
        #pragma unroll
        for (int j = 0; j < 16; ++j) {
            int k = tid + j * 256;
            if (k == 0) {
                float2 C0 = s[0];
                float U0 = C0.x + C0.y, UN = C0.x - C0.y;   // U[0], U[8192] (real)
                float Y0 = U0 * Kk[0].x, YN = UN * Kk[0].y;
                s[0] = make_float2(Y0 + YN, Y0 - YN);       // Z2[0]
                float2 C = s[1];                            // C[4096]
                float2 U = make_float2(C.x, -C.y);          // U[4096] = conj(C)
                float2 Y = cmulf(U, Km[0]);
                s[1] = make_float2(2.0f * Y.x, -2.0f * Y.y); // Z2[4096] = 2*conj(Y)
            } else {
                int m = NC - k;
                int pk = sw(rev13(k)), pm = sw(rev13(m));
                float2 Ck = s[pk], Cm = s[pm];
                float sn, cs;
                __sincosf(TWO_PI_OVER_N * (float)k, &sn, &cs);   // w = (cs,-sn)
                float2 E = make_float2(Ck.x + Cm.x, Ck.y - Cm.y);
                float2 O = make_float2(Ck.x - Cm.x, Ck.y + Cm.y);
                float2 WO = make_float2(O.x * cs + O.y * sn, -O.x * sn + O.y * cs);
                float2 T = make_float2(-WO.y, WO.x);
                float2 Uk = make_float2(0.5f * (E.x - T.x),  0.5f * (E.y - T.y));
                float2 Um = make_float2(0.5f * (E.x + T.x), -0.5f * (E.y + T.y));
                float2 Yk = cmulf(Uk, Kk[j]);
                float2 Ym = cmulf(Um, Km[j]);
                float2 P = make_float2(Yk.x + Ym.x, Yk.y - Ym.y);  // Yk + conj(Ym)
                float2 Q = make_float2(Yk.x - Ym.x, Yk.y + Ym.y);  // Yk - conj(Ym)
                float2 CQ = make_float2(Q.x * cs - Q.y * sn, Q.x * sn + Q.y * cs); // conj(w)*Q
                float2 T2 = make_float2(-CQ.y, CQ.x);              // i*conj(w)*Q
                s[pk] = make_float2(P.x + T2.x, P.y + T2.y);       // Z2[k]
                s[pm] = make_float2(P.x - T2.x, -(P.y - T2.y));    // Z2[m] = conj(P-T2)
            }
        }
        __syncthreads();

        // inverse: levels 1,2,4,8 in contiguous 16-blocks (const twiddles)
        for (int gg = 0; gg < 2; ++gg) {
            int b16 = (tid + gg * 256) << 4;
            float2 v[16];
            #pragma unroll
            for (int m = 0; m < 16; ++m) v[m] = s[sw(b16 + m)];
            dit16(v);
            #pragma unroll
            for (int m = 0; m < 16; ++m) s[sw(b16 + m)] = v[m];
        }
        __syncthreads();
        inv_pass8<16>(s, tid);
        __syncthreads();
        inv_pass8<128>(s, tid);
        __syncthreads();
        inv_last_out(s, tid, xr, (float2*)(out + base), Dd);
    }
}

extern "C" void kernel_launch(void* const* d_in, const int* in_sizes, int n_in,
                              void* d_out, int out_size, void* d_ws, size_t ws_size,
                              hipStream_t stream) {
    (void)in_sizes; (void)n_in; (void)out_size; (void)d_ws; (void)ws_size;
    const float* x    = (const float*)d_in[0];
    // d_in[1] is L (int scalar) -- constants are hardcoded (L=8192)
    const float* W1   = (const float*)d_in[2];
    const float* b1   = (const float*)d_in[3];
    const float* freq = (const float*)d_in[4];
    const float* W2   = (const float*)d_in[5];
    const float* b2   = (const float*)d_in[6];
    const float* W3   = (const float*)d_in[7];
    const float* b3   = (const float*)d_in[8];
    const float* Wout = (const float*)d_in[9];
    const float* Dv   = (const float*)d_in[10];
    float* out = (float*)d_out;

    // Time-domain filter k[1024][8192] lives in the b=0 half of d_out:
    // conv block d is the sole reader of k[d] and the sole (later) writer
    // of out[0][d] -- no cross-block hazard, no workspace needed.
    float* kbuf = out;

    hipLaunchKernelGGL(hyena_filter_k, dim3(128, 4), dim3(256), 0, stream,
                       W1, b1, freq, W2, b2, W3, b3, Wout, kbuf);
    hipLaunchKernelGGL(hyena_conv_k, dim3(1024), dim3(256), 0, stream,
                       x, kbuf, Dv, out);
}

// Round 4
// 349.899 us; speedup vs baseline: 1.8761x; 1.4799x over previous
//
#include <hip/hip_runtime.h>

#define D_MODEL 1024
#define LSEQ    8192
#define NC      8192            // complex FFT size = (2*L)/2
#define PI_F    3.14159265358979323846f
#define TWO_PI_OVER_N 3.8349519697141029e-4f   // 2*pi/16384
#define R2F  0.70710678118654752440f           // cos(pi/4)
#define C18F 0.92387953251128675613f           // cos(pi/8)
#define S18F 0.38268343236508977173f           // sin(pi/8)

// Extended XOR swizzle on LDS float2 index (bijective on [0,8192)).
__device__ __forceinline__ int sw(int p) { return p ^ ((p >> 7) & 15) ^ ((p >> 3) & 7); }
__device__ __forceinline__ int rev13(int x) { return (int)(__brev((unsigned)x) >> 19); }
__device__ __forceinline__ float2 cmulf(float2 a, float2 b) {
    return make_float2(a.x*b.x - a.y*b.y, a.x*b.y + a.y*b.x);
}

// ---- radix-2 butterflies -------------------------------------------------
__device__ __forceinline__ void bf_dif(float2& a, float2& b, float c, float s) {
    float tx = a.x - b.x, ty = a.y - b.y;
    a.x += b.x; a.y += b.y;
    b.x = tx*c - ty*s; b.y = tx*s + ty*c;
}
__device__ __forceinline__ void bf_dif1(float2& a, float2& b) {        // w = 1
    float tx = a.x - b.x, ty = a.y - b.y;
    a.x += b.x; a.y += b.y;
    b.x = tx; b.y = ty;
}
__device__ __forceinline__ void bf_dif_mi(float2& a, float2& b) {      // w = -i
    float tx = a.x - b.x, ty = a.y - b.y;
    a.x += b.x; a.y += b.y;
    b.x = ty; b.y = -tx;
}
__device__ __forceinline__ void bf_dit(float2& a, float2& b, float c, float s) {
    float bx = b.x*c - b.y*s, by = b.x*s + b.y*c;
    b.x = a.x - bx; b.y = a.y - by;
    a.x += bx; a.y += by;
}
__device__ __forceinline__ void bf_dit1(float2& a, float2& b) {        // w = 1
    float bx = b.x, by = b.y;
    b.x = a.x - bx; b.y = a.y - by;
    a.x += bx; a.y += by;
}
__device__ __forceinline__ void bf_dit_pi(float2& a, float2& b) {      // w = +i
    float bx = -b.y, by = b.x;
    b.x = a.x - bx; b.y = a.y - by;
    a.x += bx; a.y += by;
}
// DIT a-output only: a' = a + w*b   (final level where b' is dead)
__device__ __forceinline__ void bf_dit_a(float2& a, float2 b, float c, float s) {
    a.x += b.x*c - b.y*s; a.y += b.x*s + b.y*c;
}

// ---- fused forward pass: DIF levels H, H/2, H/4 (H in {512, 64}) ---------
// gg loop pinned to unroll 1: auto-unroll×4 quadruples live v[]/twiddles and
// was the round-3 VGPR-spill cause (256 VGPR, +550 MB scratch HBM traffic).
template<int H>
__device__ __forceinline__ void fwd_pass8(float2* s, int tid) {
    const float astep = -PI_F / (float)H;
    #pragma unroll 1
    for (int gg = 0; gg < 4; ++gg) {
        int gi   = tid + gg * 256;              // 1024 groups of 8
        int q    = gi & (H/4 - 1);
        int base = (gi - q) * 8 + q;            // block*2H + q
        float2 v[8];
        #pragma unroll
        for (int m = 0; m < 8; ++m) v[m] = s[sw(base + m*(H/4))];
        float a = astep * (float)q;
        float c1,s1,c2,s2,c4,s4;
        __sincosf(a,     &s1, &c1);
        __sincosf(a+a,   &s2, &c2);
        __sincosf(4.f*a, &s4, &c4);
        // level H: pairs (m, m+4), w = e^{ia} * e^{-i pi m/4}
        bf_dif(v[0], v[4], c1, s1);
        bf_dif(v[1], v[5], R2F*(c1+s1), R2F*(s1-c1));
        bf_dif(v[2], v[6], s1, -c1);
        bf_dif(v[3], v[7], R2F*(s1-c1), -R2F*(c1+s1));
        // level H/2: pairs (m, m+2); odd pairs get extra *(-i)
        bf_dif(v[0], v[2], c2, s2);  bf_dif(v[4], v[6], c2, s2);
        bf_dif(v[1], v[3], s2, -c2); bf_dif(v[5], v[7], s2, -c2);
        // level H/4: all pairs (m, m+1), w = e^{i4a}
        bf_dif(v[0], v[1], c4, s4); bf_dif(v[2], v[3], c4, s4);
        bf_dif(v[4], v[5], c4, s4); bf_dif(v[6], v[7], c4, s4);
        #pragma unroll
        for (int m = 0; m < 8; ++m) s[sw(base + m*(H/4))] = v[m];
    }
}

// ---- DIF levels 8,4,2,1 on a contiguous 16-block (all twiddles const) ----
__device__ __forceinline__ void dif16(float2* v) {
    bf_dif1 (v[0], v[8]);
    bf_dif  (v[1], v[9],   C18F, -S18F);
    bf_dif  (v[2], v[10],  R2F,  -R2F);
    bf_dif  (v[3], v[11],  S18F, -C18F);
    bf_dif_mi(v[4], v[12]);
    bf_dif  (v[5], v[13], -S18F, -C18F);
    bf_dif  (v[6], v[14], -R2F,  -R2F);
    bf_dif  (v[7], v[15], -C18F, -S18F);
    bf_dif1 (v[0], v[4]);              bf_dif1 (v[8],  v[12]);
    bf_dif  (v[1], v[5],  R2F, -R2F);  bf_dif  (v[9],  v[13],  R2F, -R2F);
    bf_dif_mi(v[2], v[6]);             bf_dif_mi(v[10], v[14]);
    bf_dif  (v[3], v[7], -R2F, -R2F);  bf_dif  (v[11], v[15], -R2F, -R2F);
    bf_dif1 (v[0], v[2]); bf_dif1 (v[4], v[6]); bf_dif1 (v[8], v[10]); bf_dif1 (v[12], v[14]);
    bf_dif_mi(v[1], v[3]); bf_dif_mi(v[5], v[7]); bf_dif_mi(v[9], v[11]); bf_dif_mi(v[13], v[15]);
    bf_dif1(v[0], v[1]); bf_dif1(v[2], v[3]);  bf_dif1(v[4], v[5]);  bf_dif1(v[6], v[7]);
    bf_dif1(v[8], v[9]); bf_dif1(v[10],v[11]); bf_dif1(v[12],v[13]); bf_dif1(v[14],v[15]);
}

// ---- full forward FFT: global (zero-padded) -> LDS, bit-reversed output --
__device__ __forceinline__ void fwd_fft(float2* s, int tid, const float2* __restrict__ g) {
    {
        const float astep = -PI_F / 4096.0f;
        #pragma unroll 1
        for (int gg = 0; gg < 4; ++gg) {
            int q = tid + gg * 256;             // 0..1023
            float2 v[8];
            #pragma unroll
            for (int m = 0; m < 4; ++m) v[m] = g[q + m*1024];
            float a = astep * (float)q;
            float c1,s1,c2,s2,c4,s4;
            __sincosf(a,     &s1, &c1);
            __sincosf(a+a,   &s2, &c2);
            __sincosf(4.f*a, &s4, &c4);
            // level 4096 vs zero upper half: v[m+4] = v[m] * (e^{ia} e^{-i pi m/4})
            float wc, ws;
            wc = c1;            ws = s1;             v[4] = make_float2(v[0].x*wc - v[0].y*ws, v[0].x*ws + v[0].y*wc);
            wc = R2F*(c1+s1);   ws = R2F*(s1-c1);    v[5] = make_float2(v[1].x*wc - v[1].y*ws, v[1].x*ws + v[1].y*wc);
            wc = s1;            ws = -c1;            v[6] = make_float2(v[2].x*wc - v[2].y*ws, v[2].x*ws + v[2].y*wc);
            wc = R2F*(s1-c1);   ws = -R2F*(c1+s1);   v[7] = make_float2(v[3].x*wc - v[3].y*ws, v[3].x*ws + v[3].y*wc);
            // level 2048
            bf_dif(v[0], v[2], c2, s2);  bf_dif(v[4], v[6], c2, s2);
            bf_dif(v[1], v[3], s2, -c2); bf_dif(v[5], v[7], s2, -c2);
            // level 1024
            bf_dif(v[0], v[1], c4, s4); bf_dif(v[2], v[3], c4, s4);
            bf_dif(v[4], v[5], c4, s4); bf_dif(v[6], v[7], c4, s4);
            #pragma unroll
            for (int m = 0; m < 8; ++m) s[sw(q + m*1024)] = v[m];
        }
    }
    __syncthreads();
    fwd_pass8<512>(s, tid);
    __syncthreads();
    fwd_pass8<64>(s, tid);
    __syncthreads();
    #pragma unroll 1
    for (int gg = 0; gg < 2; ++gg) {            // levels 8,4,2,1
        int base = (tid + gg * 256) << 4;
        float2 v[16];
        #pragma unroll
        for (int m = 0; m < 16; ++m) v[m] = s[sw(base + m)];
        dif16(v);
        #pragma unroll
        for (int m = 0; m < 16; ++m) s[sw(base + m)] = v[m];
    }
}

// ---- DIT levels 1,2,4,8 on a contiguous 16-block (const twiddles, +i) ----
__device__ __forceinline__ void dit16(float2* v) {
    bf_dit1(v[0], v[1]); bf_dit1(v[2], v[3]);  bf_dit1(v[4], v[5]);  bf_dit1(v[6], v[7]);
    bf_dit1(v[8], v[9]); bf_dit1(v[10],v[11]); bf_dit1(v[12],v[13]); bf_dit1(v[14],v[15]);
    bf_dit1 (v[0], v[2]); bf_dit_pi(v[1], v[3]);
    bf_dit1 (v[4], v[6]); bf_dit_pi(v[5], v[7]);
    bf_dit1 (v[8], v[10]); bf_dit_pi(v[9], v[11]);
    bf_dit1 (v[12],v[14]); bf_dit_pi(v[13],v[15]);
    bf_dit1 (v[0], v[4]);             bf_dit1 (v[8],  v[12]);
    bf_dit  (v[1], v[5],  R2F, R2F);  bf_dit  (v[9],  v[13],  R2F, R2F);
    bf_dit_pi(v[2], v[6]);            bf_dit_pi(v[10], v[14]);
    bf_dit  (v[3], v[7], -R2F, R2F);  bf_dit  (v[11], v[15], -R2F, R2F);
    bf_dit1 (v[0], v[8]);
    bf_dit  (v[1], v[9],   C18F, S18F);
    bf_dit  (v[2], v[10],  R2F,  R2F);
    bf_dit  (v[3], v[11],  S18F, C18F);
    bf_dit_pi(v[4], v[12]);
    bf_dit  (v[5], v[13], -S18F, C18F);
    bf_dit  (v[6], v[14], -R2F,  R2F);
    bf_dit  (v[7], v[15], -C18F, S18F);
}

// ---- fused inverse pass: DIT levels H, 2H, 4H (H in {16, 128}) -----------
template<int H>
__device__ __forceinline__ void inv_pass8(float2* s, int tid) {
    const float bstep = PI_F / (float)(4*H);
    #pragma unroll 1
    for (int gg = 0; gg < 4; ++gg) {
        int gi   = tid + gg * 256;
        int q    = gi & (H - 1);
        int base = (gi - q) * 8 + q;            // block*8H + q
        float2 v[8];
        #pragma unroll
        for (int m = 0; m < 8; ++m) v[m] = s[sw(base + m*H)];
        float bb = bstep * (float)q;
        float cb,sb,c2,s2,c4,s4;
        __sincosf(bb,      &sb, &cb);
        __sincosf(bb+bb,   &s2, &c2);
        __sincosf(4.f*bb,  &s4, &c4);
        bf_dit(v[0],v[1],c4,s4); bf_dit(v[2],v[3],c4,s4);
        bf_dit(v[4],v[5],c4,s4); bf_dit(v[6],v[7],c4,s4);
        bf_dit(v[0],v[2], c2,s2);  bf_dit(v[4],v[6], c2,s2);
        bf_dit(v[1],v[3],-s2,c2);  bf_dit(v[5],v[7],-s2,c2);
        bf_dit(v[0],v[4],  cb, sb);
        bf_dit(v[1],v[5],  R2F*(cb-sb), R2F*(sb+cb));
        bf_dit(v[2],v[6], -sb, cb);
        bf_dit(v[3],v[7], -R2F*(sb+cb), R2F*(cb-sb));
        #pragma unroll
        for (int m = 0; m < 8; ++m) s[sw(base + m*H)] = v[m];
    }
}

// ---- last inverse pass (levels 1024,2048,4096) fused with epilogue -------
// Only complex n in [0,4096) are kept (= m 0..3); store loop MUST stop at
// m<4 (channel is 4096 float2 — m>=4 is OOB on the last channel).
// x is RE-READ here (L3-resident; keeping it in regs caused the VGPR spill).
__device__ __forceinline__ void inv_last_out(const float2* s, int tid,
                                             const float2* __restrict__ xv,
                                             float2* __restrict__ ov, float Dd) {
    const float bstep = PI_F / 4096.0f;
    #pragma unroll 1
    for (int gg = 0; gg < 4; ++gg) {
        int q = tid + gg * 256;                 // single 8192-block
        float2 v[8];
        #pragma unroll
        for (int m = 0; m < 8; ++m) v[m] = s[sw(q + m*1024)];
        float bb = bstep * (float)q;
        float cb,sb,c2,s2,c4,s4;
        __sincosf(bb,      &sb, &cb);
        __sincosf(bb+bb,   &s2, &c2);
        __sincosf(4.f*bb,  &s4, &c4);
        // level 1024
        bf_dit(v[0],v[1],c4,s4); bf_dit(v[2],v[3],c4,s4);
        bf_dit(v[4],v[5],c4,s4); bf_dit(v[6],v[7],c4,s4);
        // level 2048
        bf_dit(v[0],v[2], c2,s2);  bf_dit(v[4],v[6], c2,s2);
        bf_dit(v[1],v[3],-s2,c2);  bf_dit(v[5],v[7],-s2,c2);
        // level 4096: only a-outputs (m=0..3) survive
        bf_dit_a(v[0], v[4],  cb, sb);
        bf_dit_a(v[1], v[5],  R2F*(cb-sb), R2F*(sb+cb));
        bf_dit_a(v[2], v[6], -sb, cb);
        bf_dit_a(v[3], v[7], -R2F*(sb+cb), R2F*(cb-sb));
        #pragma unroll
        for (int m = 0; m < 4; ++m) {
            int n = q + m*1024;
            float2 xx = xv[n];
            ov[n] = make_float2(v[m].x + xx.x * Dd, v[m].y + xx.y * Dd);
        }
    }
}

// ---------------------------------------------------------------------------
// Kernel 1: implicit-filter MLP + output projection + exponential modulation.
// grid (128, 8): 64 positions x 128 channels per block. Wave g owns 32
// contiguous channels -> Wout rows are wave-uniform 32-float scalar loads;
// acc[32] per thread (vs areg[64]+acc[8]) cuts VGPR so 3 waves/SIMD resident.
// ---------------------------------------------------------------------------
__global__ void __launch_bounds__(256) hyena_filter_k(
    const float* __restrict__ W1, const float* __restrict__ b1,
    const float* __restrict__ freq,
    const float* __restrict__ W2, const float* __restrict__ b2,
    const float* __restrict__ W3, const float* __restrict__ b3,
    const float* __restrict__ Wout,
    float* __restrict__ kout)
{
    __shared__ float zbuf[64][35];   // (3p+e)%32 -> 2-way (free)
    __shared__ float abuf[64][65];   // (p+o)%32  -> 2-way (free)
    __shared__ float bbuf[64][65];

    const int tid = threadIdx.x;
    const int pbase = blockIdx.x * 64;

    // phase 0: positional embedding z[p][0..32]
    for (int idx = tid; idx < 64 * 33; idx += 256) {
        int p = idx & 63, e = idx >> 6;
        int gp = pbase + p;
        float w = 7.6699039394282907e-4f * (float)gp;   // 2*pi*gp/8192
        float val;
        if (e == 0) {
            val = (float)gp / 8191.0f;
        } else if (e < 17) {
            float f = 1.0e-4f + (float)(e - 1) * ((15.0f - 1.0e-4f) / 15.0f);
            val = cosf(f * w);
        } else {
            float f = 1.0e-4f + (float)(e - 17) * ((15.0f - 1.0e-4f) / 15.0f);
            val = -sinf(f * w);
        }
        zbuf[p][e] = val;
    }
    __syncthreads();

    const int p  = tid & 63;                                       // lane-varying
    const int g4 = __builtin_amdgcn_readfirstlane(tid >> 6);       // wave-uniform
    const int ob = g4 * 16;

    // layer 1: 33 -> 64, sin(freq * (z@W1 + b1))
    {
        float acc[16];
        #pragma unroll
        for (int oo = 0; oo < 16; ++oo) acc[oo] = b1[ob + oo];
        #pragma unroll
        for (int e = 0; e < 33; ++e) {
            float ae = zbuf[p][e];
            const float* wr = W1 + e * 64 + ob;
            #pragma unroll
            for (int oo = 0; oo < 16; ++oo) acc[oo] += ae * wr[oo];
        }
        #pragma unroll
        for (int oo = 0; oo < 16; ++oo) abuf[p][ob + oo] = __sinf(freq[ob + oo] * acc[oo]);
    }
    __syncthreads();
    // layer 2
    {
        float acc[16];
        #pragma unroll
        for (int oo = 0; oo < 16; ++oo) acc[oo] = b2[ob + oo];
        #pragma unroll
        for (int e = 0; e < 64; ++e) {
            float ae = abuf[p][e];
            const float* wr = W2 + e * 64 + ob;
            #pragma unroll
            for (int oo = 0; oo < 16; ++oo) acc[oo] += ae * wr[oo];
        }
        #pragma unroll
        for (int oo = 0; oo < 16; ++oo) bbuf[p][ob + oo] = __sinf(freq[ob + oo] * acc[oo]);
    }
    __syncthreads();
    // layer 3
    {
        float acc[16];
        #pragma unroll
        for (int oo = 0; oo < 16; ++oo) acc[oo] = b3[ob + oo];
        #pragma unroll
        for (int e = 0; e < 64; ++e) {
            float ae = bbuf[p][e];
            const float* wr = W3 + e * 64 + ob;
            #pragma unroll
            for (int oo = 0; oo < 16; ++oo) acc[oo] += ae * wr[oo];
        }
        #pragma unroll
        for (int oo = 0; oo < 16; ++oo) abuf[p][ob + oo] = __sinf(freq[ob + oo] * acc[oo]);
    }
    __syncthreads();

    // out projection (no bias, no sin) + decay, write k[d][l].
    // Wave g owns channels dd0..dd0+31 (contiguous): Wout row slices are
    // wave-uniform scalar dwordx16 loads; h via conflict-free LDS b32 reads.
    {
        const int gp = pbase + p;
        const float t = (float)gp / 8191.0f;
        const float mind  = -3.0701134573253940f;    // log(0.01)/1.5
        const float dstep = -0.012004353694331942f;  // (log(.01)/.3 - log(.01)/1.5)/1023
        const int dd0 = blockIdx.y * 128 + g4 * 32;

        float acc[32];
        #pragma unroll
        for (int ii = 0; ii < 32; ++ii) acc[ii] = 0.0f;

        #pragma unroll 4
        for (int o = 0; o < 64; ++o) {
            float h = abuf[p][o];                    // (p+o)%32: 2-way, free
            const float* wr = Wout + o * 1024 + dd0; // wave-uniform -> s_load
            #pragma unroll
            for (int ii = 0; ii < 32; ++ii) acc[ii] += h * wr[ii];
        }
        #pragma unroll
        for (int ii = 0; ii < 32; ++ii) {
            int dd = dd0 + ii;
            float delta = fabsf(mind + dstep * (float)dd);
            kout[(size_t)dd * LSEQ + gp] = acc[ii] * __expf(-t * delta);
        }
    }
}

// ---------------------------------------------------------------------------
// Kernel 2: per-channel FFT causal convolution + skip.
// ---------------------------------------------------------------------------
__global__ void __launch_bounds__(256) hyena_conv_k(
    const float* __restrict__ x, const float* kin,
    const float* __restrict__ Dvec, float* out)
{
    __shared__ float2 s[NC];                     // 64 KB
    const int tid = threadIdx.x;
    const int d = blockIdx.x;
    const float Dd = Dvec[d];
    const float invN = 1.0f / 16384.0f;

    // ---- phase A: FFT of filter k[d], unpack spectrum into registers ----
    fwd_fft(s, tid, (const float2*)(kin + (size_t)d * LSEQ));
    __syncthreads();

    float2 Kk[16], Km[16];   // K[k]/N and K[8192-k]/N for k = tid + j*256
    #pragma unroll
    for (int j = 0; j < 16; ++j) {
        int k = tid + j * 256;
        if (k == 0) {
            float2 C0 = s[0];                       // sw(0)==0
            Kk[0] = make_float2((C0.x + C0.y) * invN, (C0.x - C0.y) * invN); // (K[0],K[8192])/N
            float2 C = s[1];                        // C[4096] at rev13(4096)=1, sw(1)==1
            Km[0] = make_float2(C.x * invN, -C.y * invN);                    // conj(C)/N
        } else {
            int m = NC - k;
            float2 Ck = s[sw(rev13(k))], Cm = s[sw(rev13(m))];
            float sn, cs;
            __sincosf(TWO_PI_OVER_N * (float)k, &sn, &cs);   // w = (cs,-sn)
            float2 E = make_float2(Ck.x + Cm.x, Ck.y - Cm.y); // Ck + conj(Cm)
            float2 O = make_float2(Ck.x - Cm.x, Ck.y + Cm.y); // Ck - conj(Cm)
            float2 WO = make_float2(O.x * cs + O.y * sn, -O.x * sn + O.y * cs); // w*O
            float2 T = make_float2(-WO.y, WO.x);              // i*w*O
            Kk[j] = make_float2(0.5f * invN * (E.x - T.x),  0.5f * invN * (E.y - T.y));
            Km[j] = make_float2(0.5f * invN * (E.x + T.x), -0.5f * invN * (E.y + T.y)); // conj(E+T)/2N
        }
    }

    // ---- per-batch: FFT(x) -> multiply -> IFFT (+ x*D fused) ----
    for (int b = 0; b < 2; ++b) {
        __syncthreads();   // prior readers of s are done
        const size_t base = ((size_t)b * D_MODEL + d) * LSEQ;
        fwd_fft(s, tid, (const float2*)(x + base));
        __syncthreads();

        // unpack U, multiply by filter spectrum, repack Z2 (x2 folded in),
        // all in bit-reversed layout.
        #pragma unroll
        for (int j = 0; j < 16; ++j) {
            int k = tid + j * 256;
            if (k == 0) {
                float2 C0 = s[0];
                float U0 = C0.x + C0.y, UN = C0.x - C0.y;   // U[0], U[8192] (real)
                float Y0 = U0 * Kk[0].x, YN = UN * Kk[0].y;
                s[0] = make_float2(Y0 + YN, Y0 - YN);       // Z2[0]
                float2 C = s[1];                            // C[4096]
                float2 U = make_float2(C.x, -C.y);          // U[4096] = conj(C)
                float2 Y = cmulf(U, Km[0]);
                s[1] = make_float2(2.0f * Y.x, -2.0f * Y.y); // Z2[4096] = 2*conj(Y)
            } else {
                int m = NC - k;
                int pk = sw(rev13(k)), pm = sw(rev13(m));
                float2 Ck = s[pk], Cm = s[pm];
                float sn, cs;
                __sincosf(TWO_PI_OVER_N * (float)k, &sn, &cs);   // w = (cs,-sn)
                float2 E = make_float2(Ck.x + Cm.x, Ck.y - Cm.y);
                float2 O = make_float2(Ck.x - Cm.x, Ck.y + Cm.y);
                float2 WO = make_float2(O.x * cs + O.y * sn, -O.x * sn + O.y * cs);
                float2 T = make_float2(-WO.y, WO.x);
                float2 Uk = make_float2(0.5f * (E.x - T.x),  0.5f * (E.y - T.y));
                float2 Um = make_float2(0.5f * (E.x + T.x), -0.5f * (E.y + T.y));
                float2 Yk = cmulf(Uk, Kk[j]);
                float2 Ym = cmulf(Um, Km[j]);
                float2 P = make_float2(Yk.x + Ym.x, Yk.y - Ym.y);  // Yk + conj(Ym)
                float2 Q = make_float2(Yk.x - Ym.x, Yk.y + Ym.y);  // Yk - conj(Ym)
                float2 CQ = make_float2(Q.x * cs - Q.y * sn, Q.x * sn + Q.y * cs); // conj(w)*Q
                float2 T2 = make_float2(-CQ.y, CQ.x);              // i*conj(w)*Q
                s[pk] = make_float2(P.x + T2.x, P.y + T2.y);       // Z2[k]
                s[pm] = make_float2(P.x - T2.x, -(P.y - T2.y));    // Z2[m] = conj(P-T2)
            }
        }
        __syncthreads();

        // inverse: levels 1,2,4,8 in contiguous 16-blocks (const twiddles)
        #pragma unroll 1
        for (int gg = 0; gg < 2; ++gg) {
            int b16 = (tid + gg * 256) << 4;
            float2 v[16];
            #pragma unroll
            for (int m = 0; m < 16; ++m) v[m] = s[sw(b16 + m)];
            dit16(v);
            #pragma unroll
            for (int m = 0; m < 16; ++m) s[sw(b16 + m)] = v[m];
        }
        __syncthreads();
        inv_pass8<16>(s, tid);
        __syncthreads();
        inv_pass8<128>(s, tid);
        __syncthreads();
        inv_last_out(s, tid, (const float2*)(x + base), (float2*)(out + base), Dd);
    }
}

extern "C" void kernel_launch(void* const* d_in, const int* in_sizes, int n_in,
                              void* d_out, int out_size, void* d_ws, size_t ws_size,
                              hipStream_t stream) {
    (void)in_sizes; (void)n_in; (void)out_size; (void)d_ws; (void)ws_size;
    const float* x    = (const float*)d_in[0];
    // d_in[1] is L (int scalar) -- constants are hardcoded (L=8192)
    const float* W1   = (const float*)d_in[2];
    const float* b1   = (const float*)d_in[3];
    const float* freq = (const float*)d_in[4];
    const float* W2   = (const float*)d_in[5];
    const float* b2   = (const float*)d_in[6];
    const float* W3   = (const float*)d_in[7];
    const float* b3   = (const float*)d_in[8];
    const float* Wout = (const float*)d_in[9];
    const float* Dv   = (const float*)d_in[10];
    float* out = (float*)d_out;

    // Time-domain filter k[1024][8192] lives in the b=0 half of d_out:
    // conv block d is the sole reader of k[d] and the sole (later) writer
    // of out[0][d] -- no cross-block hazard, no workspace needed.
    float* kbuf = out;

    hipLaunchKernelGGL(hyena_filter_k, dim3(128, 8), dim3(256), 0, stream,
                       W1, b1, freq, W2, b2, W3, b3, Wout, kbuf);
    hipLaunchKernelGGL(hyena_conv_k, dim3(1024), dim3(256), 0, stream,
                       x, kbuf, Dv, out);
}